// Round 1
// baseline (288.592 us; speedup 1.0000x reference)
//
#include <hip/hip_runtime.h>
#include <math.h>

// Router: B=4, S=8192, D=1024, E=64, TOP_K=2 (all fp32)
// logits[t,e] = sum_d h[t,d]*w[e,d]; softmax over e; top-2 (vals+idx); renorm.
// Output layout (fp32, concatenated flat):
//   [0,       65536)   top_k_probs   [4,8192,2]
//   [65536,   131072)  selected_experts (as float) [4,8192,2]
//   [131072,  2228224) router_logits [4,8192,64]

static constexpr int TOKENS = 32768;
static constexpr int DDIM   = 1024;
static constexpr int NEXP   = 64;
static constexpr size_t OFF_EXP = 65536;
static constexpr size_t OFF_LOG = 131072;

__global__ __launch_bounds__(256, 2)
void router_kernel(const float* __restrict__ h,
                   const float* __restrict__ w,
                   float* __restrict__ out) {
    const int tid  = threadIdx.x;
    const int lane = tid & 63;
    const int wv   = tid >> 6;
    const int tg   = lane & 15;   // token within wave
    const int eg   = lane >> 4;   // expert group (16 experts each)
    const int token = blockIdx.x * 64 + wv * 16 + tg;

    const float* __restrict__ hrow = h + (size_t)token * DDIM;
    const float* __restrict__ wb   = w + (size_t)(eg * 16) * DDIM;

    float acc[16];
#pragma unroll
    for (int j = 0; j < 16; ++j) acc[j] = 0.0f;

    // K loop in chunks of 16; chunk-local FMA chain then one add into acc
    // (halves accumulated rounding error vs one long serial chain).
    for (int k0 = 0; k0 < DDIM; k0 += 16) {
        float4 av[4];
#pragma unroll
        for (int q = 0; q < 4; ++q)
            av[q] = *reinterpret_cast<const float4*>(hrow + k0 + q * 4);
        float a[16];
#pragma unroll
        for (int q = 0; q < 4; ++q) {
            a[q * 4 + 0] = av[q].x; a[q * 4 + 1] = av[q].y;
            a[q * 4 + 2] = av[q].z; a[q * 4 + 3] = av[q].w;
        }
#pragma unroll
        for (int j = 0; j < 16; ++j) {
            const float* wr = wb + (size_t)j * DDIM + k0;
            float4 w0 = *reinterpret_cast<const float4*>(wr + 0);
            float4 w1 = *reinterpret_cast<const float4*>(wr + 4);
            float4 w2 = *reinterpret_cast<const float4*>(wr + 8);
            float4 w3 = *reinterpret_cast<const float4*>(wr + 12);
            float wf[16] = {w0.x, w0.y, w0.z, w0.w,
                            w1.x, w1.y, w1.z, w1.w,
                            w2.x, w2.y, w2.z, w2.w,
                            w3.x, w3.y, w3.z, w3.w};
            float c = a[0] * wf[0];
#pragma unroll
            for (int kk = 1; kk < 16; ++kk)
                c = fmaf(a[kk], wf[kk], c);
            acc[j] += c;
        }
    }

    // ---- write logits (coalesced: wave covers a contiguous 4 KiB span) ----
    float* lg = out + OFF_LOG + (size_t)token * NEXP + eg * 16;
#pragma unroll
    for (int q = 0; q < 4; ++q) {
        float4 v = make_float4(acc[q * 4 + 0], acc[q * 4 + 1],
                               acc[q * 4 + 2], acc[q * 4 + 3]);
        *reinterpret_cast<float4*>(lg + q * 4) = v;
    }

    // ---- softmax over 64 experts (4 lanes per token, xor 16 / 32) ----
    float m = acc[0];
#pragma unroll
    for (int j = 1; j < 16; ++j) m = fmaxf(m, acc[j]);
    m = fmaxf(m, __shfl_xor(m, 16, 64));
    m = fmaxf(m, __shfl_xor(m, 32, 64));

    float p[16];
    float s = 0.0f;
#pragma unroll
    for (int j = 0; j < 16; ++j) { p[j] = expf(acc[j] - m); s += p[j]; }
    s += __shfl_xor(s, 16, 64);
    s += __shfl_xor(s, 32, 64);

    // ---- local top-2 (ascending scan, strict '>' => lower index wins ties) ----
    float v1 = -INFINITY, v2 = -INFINITY;
    int   i1 = NEXP,      i2 = NEXP;
#pragma unroll
    for (int j = 0; j < 16; ++j) {
        float v = p[j];
        int   e = eg * 16 + j;
        if (v > v1)      { v2 = v1; i2 = i1; v1 = v; i1 = e; }
        else if (v > v2) { v2 = v;  i2 = e; }
    }

    // ---- merge top-2 across the 4 expert-group lanes ----
#pragma unroll
    for (int d = 16; d <= 32; d <<= 1) {
        float ov1 = __shfl_xor(v1, d, 64);
        float ov2 = __shfl_xor(v2, d, 64);
        int   oi1 = __shfl_xor(i1, d, 64);
        int   oi2 = __shfl_xor(i2, d, 64);
        bool ofirst = (ov1 > v1) || (ov1 == v1 && oi1 < i1);
        float n1, n2; int ni1, ni2;
        if (ofirst) {
            n1 = ov1; ni1 = oi1;
            bool sec = (v1 > ov2) || (v1 == ov2 && i1 < oi2);
            n2 = sec ? v1 : ov2; ni2 = sec ? i1 : oi2;
        } else {
            n1 = v1; ni1 = i1;
            bool sec = (ov1 > v2) || (ov1 == v2 && oi1 < i2);
            n2 = sec ? ov1 : v2; ni2 = sec ? oi1 : i2;
        }
        v1 = n1; i1 = ni1; v2 = n2; i2 = ni2;
    }

    // ---- normalize top-2 and write (lane eg==0 only) ----
    if (eg == 0) {
        float t1 = v1 / s;
        float t2 = v2 / s;
        float dn = t1 + t2 + 1e-8f;
        float2 pr; pr.x = t1 / dn; pr.y = t2 / dn;
        *reinterpret_cast<float2*>(out + (size_t)token * 2) = pr;
        float2 ex; ex.x = (float)i1; ex.y = (float)i2;
        *reinterpret_cast<float2*>(out + OFF_EXP + (size_t)token * 2) = ex;
    }
}

extern "C" void kernel_launch(void* const* d_in, const int* in_sizes, int n_in,
                              void* d_out, int out_size, void* d_ws, size_t ws_size,
                              hipStream_t stream) {
    const float* h = (const float*)d_in[0];
    const float* w = (const float*)d_in[1];
    float* out = (float*)d_out;
    dim3 grid(TOKENS / 64);
    dim3 block(256);
    hipLaunchKernelGGL(router_kernel, grid, block, 0, stream, h, w, out);
}